// Round 5
// baseline (100862.750 us; speedup 1.0000x reference)
//
#include <hip/hip_runtime.h>

typedef _Float16 f16;
typedef __attribute__((ext_vector_type(8))) _Float16 f16x8;
typedef __attribute__((ext_vector_type(4))) float f32x4;

#define LL   256
#define BB   512
#define DD   512
#define NN3  1536
#define NWG  32
#define NT   512

// ---- workspace byte offsets (packed weights only; no mutable state in ws) ----
#define OFF_WP   ((size_t)0)
#define OFF_WXP  (OFF_WP  + (size_t)64*NN3*8*2)
#define OFF_LY1P (OFF_WXP + (size_t)64*NN3*8*2)
#define OFF_WINP (OFF_LY1P+ (size_t)64*DD*8*2)
#define OFF_BF   (OFF_WINP+ (size_t)4*DD*8*2)

__device__ __forceinline__ float sigmoid_f(float x) {
  return __builtin_amdgcn_rcpf(1.f + __expf(-x));
}
__device__ __forceinline__ float tanh_f(float x) {
  float ax = fabsf(x);
  float e  = __expf(-2.f * ax);
  float t  = (1.f - e) * __builtin_amdgcn_rcpf(1.f + e);
  return copysignf(t, x);
}

// Pack weights into fp16 fragment-order layouts.
// Fused gate/lin matrix columns interleaved per 48: [z i0..i0+15 | r ... | lin ...]
__global__ void pack_kernel(const float* __restrict__ Win, const float* __restrict__ Wx,
                            const float* __restrict__ Wg,  const float* __restrict__ bg,
                            const float* __restrict__ Wlin,const float* __restrict__ blin,
                            const float* __restrict__ Ly1, char* __restrict__ ws)
{
  f16* WP   = (f16*)(ws + OFF_WP);
  f16* WXP  = (f16*)(ws + OFF_WXP);
  f16* LY1P = (f16*)(ws + OFF_LY1P);
  f16* WINP = (f16*)(ws + OFF_WINP);
  float* BF = (float*)(ws + OFF_BF);
  const int stride = gridDim.x * blockDim.x;
  const int idx0 = blockIdx.x * blockDim.x + threadIdx.x;

  for (int e = idx0; e < 64*NN3*8; e += stride) {
    int kb = e / (NN3*8); int rem = e - kb*(NN3*8); int n = rem >> 3; int h = rem & 7;
    int k = kb*8 + h;
    int ib = n/48, wi = n - ib*48; int s = wi >> 4, il = wi & 15;
    int i = ib*16 + il;
    float wv, xv;
    if (s == 0)      { wv = Wg[(size_t)i*DD + k];         xv = Wx[(size_t)i*DD + k]; }
    else if (s == 1) { wv = Wg[(size_t)(512+i)*DD + k];   xv = Wx[(size_t)(512+i)*DD + k]; }
    else             { wv = Wlin[(size_t)i*DD + k];       xv = Wx[(size_t)(1024+i)*DD + k]; }
    WP[e] = (f16)wv; WXP[e] = (f16)xv;
  }
  for (int e = idx0; e < 64*DD*8; e += stride) {
    int kb = e / (DD*8); int rem = e - kb*(DD*8); int n = rem >> 3; int h = rem & 7;
    LY1P[e] = (f16)Ly1[(size_t)n*DD + kb*8 + h];
  }
  for (int e = idx0; e < 4*DD*8; e += stride) {
    int kb = e / (DD*8); int rem = e - kb*(DD*8); int n = rem >> 3; int h = rem & 7;
    int c = kb*8 + h;
    WINP[e] = (c < 15) ? (f16)Win[n*15 + c] : (f16)0.f;
  }
  for (int n = idx0; n < NN3; n += stride) {
    int ib = n/48, wi = n - ib*48; int s = wi >> 4, il = wi & 15;
    int i = ib*16 + il;
    BF[n] = (s == 0) ? bg[i] : (s == 1) ? bg[512+i] : blin[i];
  }
}

// 32 WGs x 512 threads. WG owns 16 batch rows completely (all 512 state cols).
// h in WG-local LDS (fp16, XOR-swizzled); RK4 state + lx tile in registers.
// Weights stream from (XCD-shared) L2. Zero inter-WG communication.
__launch_bounds__(NT, 1)
__global__ void scan_kernel(const float* __restrict__ seq, const float* __restrict__ state0,
                            const float* __restrict__ bin, const float* __restrict__ Ly2,
                            float* __restrict__ out, const char* __restrict__ ws)
{
  const f16* WP   = (const f16*)(ws + OFF_WP);
  const f16* WXP  = (const f16*)(ws + OFF_WXP);
  const f16* LY1P = (const f16*)(ws + OFF_LY1P);
  const f16* WINP = (const f16*)(ws + OFF_WINP);
  const float* BF = (const float*)(ws + OFF_BF);

  __shared__ __align__(16) f16 h16s[16*512];   // 16 KB, swizzled [row][col]
  __shared__ __align__(16) f16 xe16s[16*512];  // 16 KB, swizzled
  __shared__ __align__(16) f16 sqs[16*32];     // 1 KB seq tile (k padded to 32)
  __shared__ float ybuf[16][8];
  char* h16 = (char*)h16s; char* xe16 = (char*)xe16s; char* sq = (char*)sqs;

  const int tid = threadIdx.x;
  const int w  = tid >> 6, l = tid & 63;
  const int lr = l & 15, lk = l >> 4;
  const int nws = w * 192;            // packed-col base for this wave (1536/8)
  const int m0  = blockIdx.x * 16;    // 16 batch rows per WG

  // K=512 x N=1536 GEMM: A-frags from swizzled LDS, B direct from L2-resident packed weights.
  auto gemm1536 = [&](const f16* __restrict__ B, const char* __restrict__ Alds,
                      f32x4 (&av)[4][3]) {
    #pragma unroll
    for (int ks = 0; ks < 16; ++ks) {
      f16x8 a = *(const f16x8*)(Alds + lr*1024 + ((ks*64 + lk*16) ^ ((lr & 7) << 4)));
      const f16* bk = B + ((size_t)(ks*4 + lk)*NN3 + nws + lr)*8;
      #pragma unroll
      for (int tb = 0; tb < 4; ++tb)
        #pragma unroll
        for (int s = 0; s < 3; ++s)
          av[tb][s] = __builtin_amdgcn_mfma_f32_16x16x32_f16(
              a, *(const f16x8*)(bk + (tb*48 + s*16)*8), av[tb][s], 0, 0, 0);
    }
  };

  // ---- init: h = state0 (regs + LDS fp16 mirror) ----
  float hbase[4][4], hstage[4][4], acc[4][4];
  #pragma unroll
  for (int tb = 0; tb < 4; ++tb) {
    int i = w*64 + tb*16 + lr;
    float sv = state0[i];
    #pragma unroll
    for (int r2 = 0; r2 < 4; ++r2) {
      hbase[tb][r2] = sv; hstage[tb][r2] = sv; acc[tb][r2] = 0.f;
      int row = lk*4 + r2;
      *(f16*)(h16 + row*1024 + ((i*2) ^ ((row & 7) << 4))) = (f16)sv;
    }
  }
  __syncthreads();

  #pragma unroll 1
  for (int t = 0; t < LL; ++t) {
    // ---- phase 1: ybuf zero + seq tile stage + dt loads ----
    if (tid < 128) ybuf[tid >> 3][tid & 7] = 0.f;
    if (tid < 256) {
      int r = tid >> 4, c = tid & 15;
      float v = seq[((size_t)t*BB + m0 + r)*16 + c];
      *(f16*)(sq + r*64 + ((c*2) ^ ((r & 3) << 4))) = (f16)v;
    } else {
      int r = (tid - 256) >> 4, c = 16 + ((tid - 256) & 15);
      *(f16*)(sq + r*64 + ((c*2) ^ ((r & 3) << 4))) = (f16)0.f;
    }
    float dtb[4];
    #pragma unroll
    for (int r2 = 0; r2 < 4; ++r2)
      dtb[r2] = (t == 0) ? 0.f : seq[((size_t)(t-1)*BB + m0 + lk*4 + r2)*16 + 15];
    __syncthreads();

    // ---- phase 2a: xe = tanh(x @ Win^T + bin), K=32 MFMA -> xe16 LDS ----
    {
      f16x8 a1 = *(const f16x8*)(sq + lr*64 + ((lk*16) ^ ((lr & 3) << 4)));
      #pragma unroll
      for (int nf = 0; nf < 4; ++nf) {
        int col = w*64 + nf*16 + lr;
        f16x8 b1 = *(const f16x8*)(WINP + ((size_t)lk*DD + col)*8);
        f32x4 d = {0.f,0.f,0.f,0.f};
        d = __builtin_amdgcn_mfma_f32_16x16x32_f16(a1, b1, d, 0, 0, 0);
        float bv = bin[col];
        #pragma unroll
        for (int r2 = 0; r2 < 4; ++r2) {
          int row = lk*4 + r2;
          *(f16*)(xe16 + row*1024 + ((col*2) ^ ((row & 7) << 4))) = (f16)tanh_f(d[r2] + bv);
        }
      }
    }
    // ---- phase 2b: Y head from current h16 (= h at step start) ----
    {
      f32x4 ty[4] = {{0.f,0.f,0.f,0.f},{0.f,0.f,0.f,0.f},{0.f,0.f,0.f,0.f},{0.f,0.f,0.f,0.f}};
      #pragma unroll
      for (int ks = 0; ks < 16; ++ks) {
        f16x8 a = *(const f16x8*)(h16 + lr*1024 + ((ks*64 + lk*16) ^ ((lr & 7) << 4)));
        const f16* yb = LY1P + ((size_t)(ks*4 + lk)*DD + w*64 + lr)*8;
        #pragma unroll
        for (int nf = 0; nf < 4; ++nf)
          ty[nf] = __builtin_amdgcn_mfma_f32_16x16x32_f16(
              a, *(const f16x8*)(yb + nf*16*8), ty[nf], 0, 0, 0);
      }
      float part[4][8];
      #pragma unroll
      for (int r2 = 0; r2 < 4; ++r2)
        #pragma unroll
        for (int o = 0; o < 8; ++o) part[r2][o] = 0.f;
      #pragma unroll
      for (int nf = 0; nf < 4; ++nf) {
        int col = w*64 + nf*16 + lr;
        #pragma unroll
        for (int r2 = 0; r2 < 4; ++r2) {
          float tv = tanh_f(ty[nf][r2]);
          #pragma unroll
          for (int o = 0; o < 8; ++o)
            part[r2][o] += tv * Ly2[o*DD + col];
        }
      }
      #pragma unroll
      for (int ms = 1; ms < 16; ms <<= 1)
        #pragma unroll
        for (int r2 = 0; r2 < 4; ++r2)
          #pragma unroll
          for (int o = 0; o < 8; ++o)
            part[r2][o] += __shfl_xor(part[r2][o], ms, 64);
      if (lr == 0) {
        #pragma unroll
        for (int r2 = 0; r2 < 4; ++r2)
          #pragma unroll
          for (int o = 0; o < 8; ++o)
            atomicAdd(&ybuf[lk*4 + r2][o], part[r2][o]);
      }
    }
    __syncthreads();   // xe16 ready; ybuf complete
    if (tid < 128)
      out[((size_t)t*BB + m0 + (tid >> 3))*8 + (tid & 7)] = ybuf[tid >> 3][tid & 7];

    // ---- LX: lx = xe @ Wx^T -> registers; gate biases folded in (lin bias kept separate) ----
    f32x4 lx[4][3];
    #pragma unroll
    for (int tb = 0; tb < 4; ++tb)
      #pragma unroll
      for (int s = 0; s < 3; ++s) lx[tb][s] = (f32x4){0.f,0.f,0.f,0.f};
    gemm1536(WXP, xe16, lx);
    #pragma unroll
    for (int tb = 0; tb < 4; ++tb)
      #pragma unroll
      for (int s = 0; s < 3; ++s) {
        float bv = BF[nws + tb*48 + s*16 + lr];
        #pragma unroll
        for (int r2 = 0; r2 < 4; ++r2) lx[tb][s][r2] += bv;
      }

    // ---- 4 RK4 f-evals; all state WG-local ----
    if (t < LL-1) {
      #pragma unroll 1
      for (int j = 0; j < 4; ++j) {
        f32x4 av[4][3];
        #pragma unroll
        for (int tb = 0; tb < 4; ++tb) {
          av[tb][0] = lx[tb][0];              // z: pre-accumulate lx+bias as C-init
          av[tb][1] = lx[tb][1];              // r: same
          av[tb][2] = (f32x4){0.f,0.f,0.f,0.f};  // lin GEMM kept raw (scaled by r later)
        }
        gemm1536(WP, h16, av);
        __syncthreads();   // all waves' h16 A-reads done
        #pragma unroll
        for (int tb = 0; tb < 4; ++tb) {
          int i = w*64 + tb*16 + lr;
          #pragma unroll
          for (int r2 = 0; r2 < 4; ++r2) {
            float z   = sigmoid_f(av[tb][0][r2]);
            float rg  = sigmoid_f(av[tb][1][r2]);
            float lin = tanh_f(lx[tb][2][r2] + rg*av[tb][2][r2]);
            float kk  = z * (lin - hstage[tb][r2]);     // MEANDT == 1
            float hn;
            if (j == 0)      { acc[tb][r2] = kk;        hn = hbase[tb][r2] + 0.5f*dtb[r2]*kk; }
            else if (j == 1) { acc[tb][r2] += 2.f*kk;   hn = hbase[tb][r2] + 0.5f*dtb[r2]*kk; }
            else if (j == 2) { acc[tb][r2] += 2.f*kk;   hn = hbase[tb][r2] + dtb[r2]*kk; }
            else { hn = hbase[tb][r2] + dtb[r2]*(acc[tb][r2] + kk)*(1.f/6.f); hbase[tb][r2] = hn; }
            hstage[tb][r2] = hn;
            int row = lk*4 + r2;
            *(f16*)(h16 + row*1024 + ((i*2) ^ ((row & 7) << 4))) = (f16)hn;
          }
        }
        __syncthreads();   // h16 updated for next phase
      }
    }
  }
}

extern "C" void kernel_launch(void* const* d_in, const int* in_sizes, int n_in,
                              void* d_out, int out_size, void* d_ws, size_t ws_size,
                              hipStream_t stream)
{
  const float* seq    = (const float*)d_in[0];
  const float* state0 = (const float*)d_in[1];
  const float* Win    = (const float*)d_in[2];
  const float* bin_   = (const float*)d_in[3];
  const float* Wx     = (const float*)d_in[4];
  const float* Wg     = (const float*)d_in[5];
  const float* bg     = (const float*)d_in[6];
  const float* Wlin   = (const float*)d_in[7];
  const float* blin   = (const float*)d_in[8];
  const float* Ly1    = (const float*)d_in[9];
  const float* Ly2    = (const float*)d_in[10];
  char* ws = (char*)d_ws;

  pack_kernel<<<dim3(512), dim3(256), 0, stream>>>(Win, Wx, Wg, bg, Wlin, blin, Ly1, ws);
  scan_kernel<<<dim3(NWG), dim3(NT), 0, stream>>>(seq, state0, bin_, Ly2, (float*)d_out, ws);
}

// Round 6
// 32545.023 us; speedup vs baseline: 3.0992x; 3.0992x over previous
//
#include <hip/hip_runtime.h>

typedef _Float16 f16;
typedef __attribute__((ext_vector_type(8))) _Float16 f16x8;
typedef __attribute__((ext_vector_type(4))) float f32x4;

#define LL   256
#define BB   512
#define DD   512
#define NN3  1536
#define NWG  32
#define NT   512

#define OFF_WP   ((size_t)0)
#define OFF_WXP  (OFF_WP  + (size_t)64*NN3*8*2)
#define OFF_LY1P (OFF_WXP + (size_t)64*NN3*8*2)
#define OFF_WINP (OFF_LY1P+ (size_t)64*DD*8*2)
#define OFF_BF   (OFF_WINP+ (size_t)4*DD*8*2)
#define OFF_LXG  (OFF_BF  + (size_t)NN3*4)

#define LXS 1540
#define SMEM_BYTES (19456 + 16*LXS*4)

__device__ __forceinline__ float sigmoid_f(float x) {
  return __builtin_amdgcn_rcpf(1.f + __expf(-x));
}
__device__ __forceinline__ float tanh_f(float x) {
  float ax = fabsf(x);
  float e  = __expf(-2.f * ax);
  float t  = (1.f - e) * __builtin_amdgcn_rcpf(1.f + e);
  return copysignf(t, x);
}

__global__ void pack_kernel(const float* __restrict__ Win, const float* __restrict__ Wx,
                            const float* __restrict__ Wg,  const float* __restrict__ bg,
                            const float* __restrict__ Wlin,const float* __restrict__ blin,
                            const float* __restrict__ Ly1, char* __restrict__ ws)
{
  f16* WP   = (f16*)(ws + OFF_WP);
  f16* WXP  = (f16*)(ws + OFF_WXP);
  f16* LY1P = (f16*)(ws + OFF_LY1P);
  f16* WINP = (f16*)(ws + OFF_WINP);
  float* BF = (float*)(ws + OFF_BF);
  const int stride = gridDim.x * blockDim.x;
  const int idx0 = blockIdx.x * blockDim.x + threadIdx.x;

  for (int e = idx0; e < 64*NN3*8; e += stride) {
    int kb = e / (NN3*8); int rem = e - kb*(NN3*8); int n = rem >> 3; int h = rem & 7;
    int k = kb*8 + h;
    int ib = n/48, wi = n - ib*48; int s = wi >> 4, il = wi & 15;
    int i = ib*16 + il;
    float wv, xv;
    if (s == 0)      { wv = Wg[(size_t)i*DD + k];         xv = Wx[(size_t)i*DD + k]; }
    else if (s == 1) { wv = Wg[(size_t)(512+i)*DD + k];   xv = Wx[(size_t)(512+i)*DD + k]; }
    else             { wv = Wlin[(size_t)i*DD + k];       xv = Wx[(size_t)(1024+i)*DD + k]; }
    WP[e] = (f16)wv; WXP[e] = (f16)xv;
  }
  for (int e = idx0; e < 64*DD*8; e += stride) {
    int kb = e / (DD*8); int rem = e - kb*(DD*8); int n = rem >> 3; int h = rem & 7;
    LY1P[e] = (f16)Ly1[(size_t)n*DD + kb*8 + h];
  }
  for (int e = idx0; e < 4*DD*8; e += stride) {
    int kb = e / (DD*8); int rem = e - kb*(DD*8); int n = rem >> 3; int h = rem & 7;
    int c = kb*8 + h;
    WINP[e] = (c < 15) ? (f16)Win[n*15 + c] : (f16)0.f;
  }
  for (int n = idx0; n < NN3; n += stride) {
    int ib = n/48, wi = n - ib*48; int s = wi >> 4, il = wi & 15;
    int i = ib*16 + il;
    BF[n] = (s == 0) ? bg[i] : (s == 1) ? bg[512+i] : blin[i];
  }
}

__launch_bounds__(NT, 1)
__global__ void scan_kernel(const float* __restrict__ seq, const float* __restrict__ state0,
                            const float* __restrict__ bin, const float* __restrict__ Ly2,
                            float* __restrict__ out, char* __restrict__ ws)
{
  const f16* WP   = (const f16*)(ws + OFF_WP);
  const f16* WXP  = (const f16*)(ws + OFF_WXP);
  const f16* LY1P = (const f16*)(ws + OFF_LY1P);
  const f16* WINP = (const f16*)(ws + OFF_WINP);
  const float* BF = (const float*)(ws + OFF_BF);

  extern __shared__ __align__(16) char smem[];
  char*  h16c = smem;                      // [0,16K) h16 swizzled
  char*  sqc  = smem + 16384;              // 2 KB seq tiles
  float* ybuf = (float*)(smem + 18432);    // 512 B
  float* lxsh = (float*)(smem + 19456);    // [16][LXS] f32; head aliased by xe16[2]
  char*  xec  = smem + 19456;

  const int tid = threadIdx.x;
  const int w  = tid >> 6, l = tid & 63;
  const int lr = l & 15, lk = l >> 4;
  const int nws = w * 192;
  const int m0  = blockIdx.x * 16;

  float* myLxg = (float*)(ws + OFF_LXG) + (size_t)blockIdx.x * 16 * NN3;

  float hbase[4][4], hstage[4][4], acc[4][4];
  #pragma unroll
  for (int tb = 0; tb < 4; ++tb) {
    int i = (w*4 + tb)*16 + lr;
    float sv = state0[i];
    #pragma unroll
    for (int r2 = 0; r2 < 4; ++r2) {
      hbase[tb][r2] = sv; hstage[tb][r2] = sv; acc[tb][r2] = 0.f;
    }
  }
  for (int e = tid; e < 8192; e += NT) {
    int r = e >> 9, c = e & 511;
    *(f16*)(h16c + r*1024 + ((c*2) ^ ((r & 7) << 4))) = (f16)state0[c];
  }
  __syncthreads();

  #pragma unroll 1
  for (int t = 0; t < LL; ++t) {
    float dtb[4];
    #pragma unroll
    for (int r2 = 0; r2 < 4; ++r2)
      dtb[r2] = (t == 0) ? 0.f : seq[((size_t)(t-1)*BB + m0 + lk*4 + r2)*16 + 15];

    if ((t & 1) == 0) {
      // chunk: lx for steps t,t+1 in one WXP pass
      if (tid < 128) ((float*)ybuf)[tid] = 0.f;
      for (int e = tid; e < 1024; e += NT) {
        int s = e >> 9, rem = e & 511, r = rem >> 5, c = rem & 31;
        f16 v = (f16)0.f;
        if (c < 16) v = (f16)seq[((size_t)(t+s)*BB + m0 + r)*16 + c];
        *(f16*)(sqc + s*1024 + r*64 + ((c*2) ^ ((r & 3) << 4))) = v;
      }
      __syncthreads();
      #pragma unroll
      for (int s = 0; s < 2; ++s) {
        f16x8 a1 = *(const f16x8*)(sqc + s*1024 + lr*64 + ((lk*16) ^ ((lr & 3) << 4)));
        #pragma unroll
        for (int nf = 0; nf < 4; ++nf) {
          int col = w*64 + nf*16 + lr;
          f16x8 b1 = *(const f16x8*)(WINP + ((size_t)lk*DD + col)*8);
          f32x4 d = {0.f,0.f,0.f,0.f};
          d = __builtin_amdgcn_mfma_f32_16x16x32_f16(a1, b1, d, 0, 0, 0);
          float bv = bin[col];
          #pragma unroll
          for (int r2 = 0; r2 < 4; ++r2) {
            int row = lk*4 + r2;
            *(f16*)(xec + s*16384 + row*1024 + ((col*2) ^ ((row & 7) << 4)))
                = (f16)tanh_f(d[r2] + bv);
          }
        }
      }
      __syncthreads();
      f32x4 lxa0[4][3], lxa1[4][3];
      #pragma unroll
      for (int tb = 0; tb < 4; ++tb)
        #pragma unroll
        for (int s3 = 0; s3 < 3; ++s3) {
          lxa0[tb][s3] = (f32x4){0.f,0.f,0.f,0.f};
          lxa1[tb][s3] = (f32x4){0.f,0.f,0.f,0.f};
        }
      #pragma unroll 4
      for (int ks = 0; ks < 16; ++ks) {
        const f16* bk = WXP + ((size_t)(ks*4 + lk)*NN3 + nws + lr)*8;
        int axo = (ks*64 + lk*16) ^ ((lr & 7) << 4);
        f16x8 a0 = *(const f16x8*)(xec +         lr*1024 + axo);
        f16x8 a1 = *(const f16x8*)(xec + 16384 + lr*1024 + axo);
        #pragma unroll
        for (int tb = 0; tb < 4; ++tb)
          #pragma unroll
          for (int s3 = 0; s3 < 3; ++s3) {
            f16x8 b = *(const f16x8*)(bk + (tb*48 + s3*16)*8);
            lxa0[tb][s3] = __builtin_amdgcn_mfma_f32_16x16x32_f16(a0, b, lxa0[tb][s3], 0, 0, 0);
            lxa1[tb][s3] = __builtin_amdgcn_mfma_f32_16x16x32_f16(a1, b, lxa1[tb][s3], 0, 0, 0);
          }
      }
      __syncthreads();
      #pragma unroll
      for (int tb = 0; tb < 4; ++tb)
        #pragma unroll
        for (int s3 = 0; s3 < 3; ++s3) {
          int n = nws + tb*48 + s3*16 + lr;
          float bv = BF[n];
          #pragma unroll
          for (int r2 = 0; r2 < 4; ++r2) {
            int row = lk*4 + r2;
            lxsh[row*LXS + n]          = lxa0[tb][s3][r2] + bv;
            myLxg[(size_t)row*NN3 + n] = lxa1[tb][s3][r2] + bv;
          }
        }
    } else {
      if (tid < 128) ((float*)ybuf)[tid] = 0.f;
      for (int e = tid; e < 6144; e += NT) {
        int r = e / 384, q = (e - r*384) * 4;
        *(float4*)&lxsh[r*LXS + q] = *(const float4*)&myLxg[(size_t)r*NN3 + q];
      }
    }

    // Y head from step-start h
    {
      f32x4 ty[4] = {{0.f,0.f,0.f,0.f},{0.f,0.f,0.f,0.f},{0.f,0.f,0.f,0.f},{0.f,0.f,0.f,0.f}};
      #pragma unroll
      for (int ks = 0; ks < 16; ++ks) {
        f16x8 a = *(const f16x8*)(h16c + lr*1024 + ((ks*64 + lk*16) ^ ((lr & 7) << 4)));
        const f16* yb = LY1P + ((size_t)(ks*4 + lk)*DD + w*64 + lr)*8;
        #pragma unroll
        for (int nf = 0; nf < 4; ++nf)
          ty[nf] = __builtin_amdgcn_mfma_f32_16x16x32_f16(
              a, *(const f16x8*)(yb + nf*16*8), ty[nf], 0, 0, 0);
      }
      float part[4][8];
      #pragma unroll
      for (int r2 = 0; r2 < 4; ++r2)
        #pragma unroll
        for (int o = 0; o < 8; ++o) part[r2][o] = 0.f;
      #pragma unroll
      for (int nf = 0; nf < 4; ++nf) {
        int col = w*64 + nf*16 + lr;
        #pragma unroll
        for (int r2 = 0; r2 < 4; ++r2) {
          float tv = tanh_f(ty[nf][r2]);
          #pragma unroll
          for (int o = 0; o < 8; ++o)
            part[r2][o] += tv * Ly2[o*DD + col];
        }
      }
      #pragma unroll
      for (int ms = 1; ms < 16; ms <<= 1)
        #pragma unroll
        for (int r2 = 0; r2 < 4; ++r2)
          #pragma unroll
          for (int o = 0; o < 8; ++o)
            part[r2][o] += __shfl_xor(part[r2][o], ms, 64);
      if (lr == 0) {
        #pragma unroll
        for (int r2 = 0; r2 < 4; ++r2)
          #pragma unroll
          for (int o = 0; o < 8; ++o)
            atomicAdd(&ybuf[(lk*4 + r2)*8 + o], part[r2][o]);
      }
    }
    __syncthreads();
    if (tid < 128)
      out[((size_t)t*BB + m0 + (tid >> 3))*8 + (tid & 7)] = ((float*)ybuf)[tid];

    // 4 RK4 f-evals; register-double-buffered WP stream
    if (t < LL-1) {
      #pragma unroll 1
      for (int j = 0; j < 4; ++j) {
        f32x4 av[4][3];
        #pragma unroll
        for (int tb = 0; tb < 4; ++tb)
          #pragma unroll
          for (int s3 = 0; s3 < 3; ++s3) av[tb][s3] = (f32x4){0.f,0.f,0.f,0.f};

        f16x8 bc[12], bn[12];
        {
          const f16* bk = WP + ((size_t)lk*NN3 + nws + lr)*8;
          #pragma unroll
          for (int tb = 0; tb < 4; ++tb)
            #pragma unroll
            for (int s3 = 0; s3 < 3; ++s3)
              bc[tb*3 + s3] = *(const f16x8*)(bk + (tb*48 + s3*16)*8);
        }
        #pragma unroll
        for (int ks = 0; ks < 16; ++ks) {
          if (ks < 15) {
            const f16* bk = WP + ((size_t)((ks+1)*4 + lk)*NN3 + nws + lr)*8;
            #pragma unroll
            for (int tb = 0; tb < 4; ++tb)
              #pragma unroll
              for (int s3 = 0; s3 < 3; ++s3)
                bn[tb*3 + s3] = *(const f16x8*)(bk + (tb*48 + s3*16)*8);
          }
          f16x8 a = *(const f16x8*)(h16c + lr*1024 + ((ks*64 + lk*16) ^ ((lr & 7) << 4)));
          #pragma unroll
          for (int tb = 0; tb < 4; ++tb)
            #pragma unroll
            for (int s3 = 0; s3 < 3; ++s3)
              av[tb][s3] = __builtin_amdgcn_mfma_f32_16x16x32_f16(a, bc[tb*3 + s3], av[tb][s3], 0, 0, 0);
          #pragma unroll
          for (int q = 0; q < 12; ++q) bc[q] = bn[q];
        }
        __syncthreads();   // all h16 A-reads done
        #pragma unroll
        for (int tb = 0; tb < 4; ++tb) {
          int i = (w*4 + tb)*16 + lr;
          int nb = nws + tb*48 + lr;
          #pragma unroll
          for (int r2 = 0; r2 < 4; ++r2) {
            int row = lk*4 + r2;
            float z   = sigmoid_f(av[tb][0][r2] + lxsh[row*LXS + nb]);
            float rg  = sigmoid_f(av[tb][1][r2] + lxsh[row*LXS + nb + 16]);
            float lin = tanh_f(lxsh[row*LXS + nb + 32] + rg*av[tb][2][r2]);
            float kk  = z * (lin - hstage[tb][r2]);     // MEANDT == 1
            float hn;
            if (j == 0)      { acc[tb][r2] = kk;        hn = hbase[tb][r2] + 0.5f*dtb[r2]*kk; }
            else if (j == 1) { acc[tb][r2] += 2.f*kk;   hn = hbase[tb][r2] + 0.5f*dtb[r2]*kk; }
            else if (j == 2) { acc[tb][r2] += 2.f*kk;   hn = hbase[tb][r2] + dtb[r2]*kk; }
            else { hn = hbase[tb][r2] + dtb[r2]*(acc[tb][r2] + kk)*(1.f/6.f); hbase[tb][r2] = hn; }
            hstage[tb][r2] = hn;
            *(f16*)(h16c + row*1024 + ((i*2) ^ ((row & 7) << 4))) = (f16)hn;
          }
        }
        __syncthreads();   // h16 ready for next phase
      }
    }
  }
}

extern "C" void kernel_launch(void* const* d_in, const int* in_sizes, int n_in,
                              void* d_out, int out_size, void* d_ws, size_t ws_size,
                              hipStream_t stream)
{
  const float* seq    = (const float*)d_in[0];
  const float* state0 = (const float*)d_in[1];
  const float* Win    = (const float*)d_in[2];
  const float* bin_   = (const float*)d_in[3];
  const float* Wx     = (const float*)d_in[4];
  const float* Wg     = (const float*)d_in[5];
  const float* bg     = (const float*)d_in[6];
  const float* Wlin   = (const float*)d_in[7];
  const float* blin   = (const float*)d_in[8];
  const float* Ly1    = (const float*)d_in[9];
  const float* Ly2    = (const float*)d_in[10];
  char* ws = (char*)d_ws;

  hipFuncSetAttribute((const void*)scan_kernel,
                      hipFuncAttributeMaxDynamicSharedMemorySize, SMEM_BYTES);

  pack_kernel<<<dim3(512), dim3(256), 0, stream>>>(Win, Wx, Wg, bg, Wlin, blin, Ly1, ws);
  scan_kernel<<<dim3(NWG), dim3(NT), SMEM_BYTES, stream>>>(seq, state0, bin_, Ly2, (float*)d_out, ws);
}

// Round 7
// 14566.345 us; speedup vs baseline: 6.9244x; 2.2343x over previous
//
#include <hip/hip_runtime.h>

typedef _Float16 f16;
typedef __attribute__((ext_vector_type(8))) _Float16 f16x8;
typedef __attribute__((ext_vector_type(4))) float f32x4;

#define LL   256
#define BB   512
#define DD   512
#define NN3  1536
#define NWG  256
// LDS: [0,96K) WPl resident | [96K,108K) bschar (WXP stream / seq tile) | [108K,140K) xesh
#define SMEM_BYTES (98304 + 12288 + 32768)

// ---- workspace byte offsets ----
#define OFF_BAR    ((size_t)0)
#define OFF_HSA    ((size_t)8192)
#define OFF_HSB    (OFF_HSA  + (size_t)BB*DD*2)
#define OFF_HB16   (OFF_HSB  + (size_t)BB*DD*2)
#define OFF_WP     (OFF_HB16 + (size_t)BB*DD*2)
#define OFF_WXP    (OFF_WP   + (size_t)64*NN3*8*2)
#define OFF_LY1P   (OFF_WXP  + (size_t)64*NN3*8*2)
#define OFF_WINP   (OFF_LY1P + (size_t)64*DD*8*2)
#define OFF_BF     (OFF_WINP + (size_t)4*DD*8*2)

__device__ __forceinline__ float sigmoid_f(float x) {
  return __builtin_amdgcn_rcpf(1.f + __expf(-x));
}
__device__ __forceinline__ float tanh_f(float x) {
  float ax = fabsf(x);
  float e  = __expf(-2.f * ax);
  float t  = (1.f - e) * __builtin_amdgcn_rcpf(1.f + e);
  return copysignf(t, x);
}

// ---- direct-to-L3 (coherence-point) access helpers: bypass L1/L2, no cache-wide ops ----
__device__ __forceinline__ void ld_b128_sc(f16x8* dst, const f16* p) {
  asm volatile("global_load_dwordx4 %0, %1, off sc0 sc1" : "=v"(*dst) : "v"(p) : "memory");
}
__device__ __forceinline__ void st_f16_sc(f16* p, f16 v) {
  unsigned short u;
  __builtin_memcpy(&u, &v, 2);
  asm volatile("global_store_short %0, %1, off sc0 sc1" :: "v"(p), "v"(u) : "memory");
}
__device__ __forceinline__ void vm_drain() {
  asm volatile("s_waitcnt vmcnt(0)" ::: "memory");
}

// Pack weights into fp16 fragment-order layouts.
// Fused gate/lin matrix columns interleaved per 48: [z i0..i0+15 | r ... | lin ...]
__global__ void pack_kernel(const float* __restrict__ Win, const float* __restrict__ Wx,
                            const float* __restrict__ Wg,  const float* __restrict__ bg,
                            const float* __restrict__ Wlin,const float* __restrict__ blin,
                            const float* __restrict__ Ly1, char* __restrict__ ws)
{
  f16* WP   = (f16*)(ws + OFF_WP);
  f16* WXP  = (f16*)(ws + OFF_WXP);
  f16* LY1P = (f16*)(ws + OFF_LY1P);
  f16* WINP = (f16*)(ws + OFF_WINP);
  float* BF = (float*)(ws + OFF_BF);
  const int stride = gridDim.x * blockDim.x;
  const int idx0 = blockIdx.x * blockDim.x + threadIdx.x;

  for (int e = idx0; e < 64*NN3*8; e += stride) {
    int kb = e / (NN3*8); int rem = e - kb*(NN3*8); int n = rem >> 3; int h = rem & 7;
    int k = kb*8 + h;
    int ib = n/48, wi = n - ib*48; int s = wi >> 4, il = wi & 15;
    int i = ib*16 + il;
    float wv, xv;
    if (s == 0)      { wv = Wg[(size_t)i*DD + k];         xv = Wx[(size_t)i*DD + k]; }
    else if (s == 1) { wv = Wg[(size_t)(512+i)*DD + k];   xv = Wx[(size_t)(512+i)*DD + k]; }
    else             { wv = Wlin[(size_t)i*DD + k];       xv = Wx[(size_t)(1024+i)*DD + k]; }
    WP[e] = (f16)wv; WXP[e] = (f16)xv;
  }
  for (int e = idx0; e < 64*DD*8; e += stride) {
    int kb = e / (DD*8); int rem = e - kb*(DD*8); int n = rem >> 3; int h = rem & 7;
    LY1P[e] = (f16)Ly1[(size_t)n*DD + kb*8 + h];
  }
  for (int e = idx0; e < 4*DD*8; e += stride) {
    int kb = e / (DD*8); int rem = e - kb*(DD*8); int n = rem >> 3; int h = rem & 7;
    int c = kb*8 + h;
    WINP[e] = (c < 15) ? (f16)Win[n*15 + c] : (f16)0.f;
  }
  for (int n = idx0; n < NN3; n += stride) {
    int ib = n/48, wi = n - ib*48; int s = wi >> 4, il = wi & 15;
    int i = ib*16 + il;
    BF[n] = (s == 0) ? bg[i] : (s == 1) ? bg[512+i] : blin[i];
  }
}

__launch_bounds__(256, 1)
__global__ void scan_kernel(const float* __restrict__ seq, const float* __restrict__ state0,
                            const float* __restrict__ bin, const float* __restrict__ Ly2,
                            float* __restrict__ out, char* __restrict__ ws)
{
  f16*   hsA   = (f16*)(ws + OFF_HSA);    // stage buffers (fp16 A-operand), ping-pong
  f16*   hsB   = (f16*)(ws + OFF_HSB);
  f16*   hb16  = (f16*)(ws + OFF_HB16);   // step-base h (fp16 A-operand, j0 + Y)
  const f16* WP   = (const f16*)(ws + OFF_WP);
  const f16* WXP  = (const f16*)(ws + OFF_WXP);
  const f16* LY1P = (const f16*)(ws + OFF_LY1P);
  const f16* WINP = (const f16*)(ws + OFF_WINP);
  const float* BF = (const float*)(ws + OFF_BF);

  extern __shared__ __align__(16) char smem[];
  char* bschar = smem + 98304;     // 12 KB stream buffer (WXP slices / seq tile)
  char* xechar = smem + 110592;    // 32 KB xe tile (row-major [32][512] f16, XOR-swizzled)

  const int wg = blockIdx.x;
  const int mg = wg & 15, ng = wg >> 4;    // group = same mg (16 WGs)
  const int m0 = mg << 5;                  // 32 batch rows
  const int n0 = ng * 96;                  // 96 packed cols
  const int tid = threadIdx.x;
  const int w  = tid >> 6, l = tid & 63;
  const int mw = (w & 1) << 4;
  const int nw = (w >> 1) * 48;
  const int lr = l & 15, lk = l >> 4;

  int* bline = (int*)(ws + OFF_BAR) + mg*64;   // per-group barrier word (count | gen<<16)

  // Fence-free group barrier: RMW-only (cross-XCD-safe), no release/acquire cache ops.
  auto gbar = [&]() {
    vm_drain();            // our asm sc-stores are untracked by the compiler: drain per-wave
    __syncthreads();
    if (tid == 0) {
      int old = __hip_atomic_fetch_add(bline, 1, __ATOMIC_RELAXED, __HIP_MEMORY_SCOPE_AGENT);
      int g = old >> 16;
      if ((old & 0xFFFF) == 15) {
        __hip_atomic_fetch_add(bline, 0x10000 - 16, __ATOMIC_RELAXED, __HIP_MEMORY_SCOPE_AGENT);
      } else {
        while ((__hip_atomic_load(bline, __ATOMIC_RELAXED, __HIP_MEMORY_SCOPE_AGENT) >> 16) == g)
          __builtin_amdgcn_s_sleep(2);
      }
    }
    __syncthreads();
  };

  // ---- stage resident WP slice into LDS (once), XOR-swizzled 16B granules ----
  for (int g = tid; g < 6144; g += 256) {
    int kb = g / 96, nl = g - kb*96;
    int dst = (kb*1536 + nl*16) ^ ((kb & 7) << 4);
    *(float4*)(smem + dst) = *(const float4*)(WP + ((size_t)kb*NN3 + n0 + nl)*8);
  }
  // ---- init hb16 (this WG's 32 rows x 32 state cols) via coherence-point stores ----
  for (int e = tid; e < 1024; e += 256) {
    int r = e >> 5, c = e & 31;
    st_f16_sc(hb16 + (size_t)(m0+r)*DD + (ng<<5) + c, (f16)state0[(ng<<5)+c]);
  }
  const int iw = (ng<<5) + ((w>>1)<<4) + lr;
  float hbase[4], hstage[4], acc[4];
  {
    float sv = state0[iw];
    #pragma unroll
    for (int r2 = 0; r2 < 4; ++r2) { hbase[r2] = sv; hstage[r2] = sv; acc[r2] = 0.f; }
  }
  const float bfz = BF[n0+nw+lr], bfr = BF[n0+nw+16+lr], bfl = BF[n0+nw+32+lr];
  const int c0 = (ng<<5) + ((w>>1)<<4);
  float l2[8];
  #pragma unroll
  for (int o = 0; o < 8; ++o) l2[o] = Ly2[o*DD + c0 + lr];
  const size_t gibase = (size_t)(m0 + mw + (lk<<2))*DD + iw;
  gbar();   // hb16 visible group-wide

  f32x4 alx0, alx1, alx2;

  #pragma unroll 1
  for (int t = 0; t < LL; ++t) {
    const bool last = (t == LL-1);
    float dtb[4];
    if (!last) {
      // --- seq tile -> bschar (fp16, 16B-granule XOR swizzle), cols 16..31 zeroed ---
      {
        int tt = tid & 127;
        int r = tt >> 2, cq = tt & 3;
        int gq = (tid < 128 ? 0 : 2) + (cq >> 1), hf = cq & 1;
        f16* p = (f16*)(bschar + r*64 + ((gq ^ (r & 3))*16) + hf*8);
        if (tid < 128) {
          float4 v = *(const float4*)(seq + (((size_t)t*BB + m0 + r) << 4) + cq*4);
          p[0]=(f16)v.x; p[1]=(f16)v.y; p[2]=(f16)v.z; p[3]=(f16)v.w;
        } else { p[0]=(f16)0.f; p[1]=(f16)0.f; p[2]=(f16)0.f; p[3]=(f16)0.f; }
      }
      #pragma unroll
      for (int r2 = 0; r2 < 4; ++r2)
        dtb[r2] = (t == 0) ? 0.f
                 : seq[(((size_t)(t-1)*BB + m0 + mw + (lk<<2) + r2) << 4) + 15];
      __syncthreads();
      // --- xe = tanh(seq_x @ Win^T + bin), K=32 MFMA -> xesh (LDS, XOR-swizzled rows) ---
      #pragma unroll
      for (int rf = 0; rf < 2; ++rf) {
        int ar = rf*16 + lr;
        f16x8 a1 = *(const f16x8*)(bschar + ar*64 + ((lk ^ (ar & 3))*16));
        #pragma unroll
        for (int cf = 0; cf < 8; ++cf) {
          int col = (w << 7) + (cf << 4) + lr;
          f16x8 b1 = *(const f16x8*)(WINP + ((size_t)lk*DD + col)*8);
          f32x4 d = {0.f,0.f,0.f,0.f};
          d = __builtin_amdgcn_mfma_f32_16x16x32_f16(a1, b1, d, 0, 0, 0);
          float bv = bin[col];
          #pragma unroll
          for (int r2 = 0; r2 < 4; ++r2) {
            int row = rf*16 + (lk << 2) + r2;
            *(f16*)(xechar + row*1024 + ((col*2) ^ ((row & 7) << 4))) = (f16)tanh_f(d[r2] + bv);
          }
        }
      }
      __syncthreads();   // bschar reads done (reusable); xesh visible
      // --- LX: alx = xe @ WXP ; A from xesh, B streamed WXP->bschar (L2-hot, plain) ---
      {
        f16x8 axf[16];
        {
          const int row = mw + lr;
          #pragma unroll
          for (int ks = 0; ks < 16; ++ks)
            axf[ks] = *(const f16x8*)(xechar + row*1024 + ((lk*16 + ks*64) ^ ((row & 7) << 4)));
        }
        const int kb0 = tid/96,        nn0p = tid - kb0*96;
        const int kb1 = (tid+256)/96,  nn1p = (tid+256) - kb1*96;
        const int kb2 = (tid+512)/96,  nn2p = (tid+512) - kb2*96;
        const int d0 = (kb0*1536 + nn0p*16) ^ (kb0 << 4);
        const int d1 = (kb1*1536 + nn1p*16) ^ (kb1 << 4);
        const int d2 = (kb2*1536 + nn2p*16) ^ (kb2 << 4);
        float4 s0 = *(const float4*)(WXP + ((size_t)kb0*NN3 + n0 + nn0p)*8);
        float4 s1 = *(const float4*)(WXP + ((size_t)kb1*NN3 + n0 + nn1p)*8);
        float4 s2 = *(const float4*)(WXP + ((size_t)kb2*NN3 + n0 + nn2p)*8);
        f32x4 L0 = {0.f,0.f,0.f,0.f}, L1 = L0, L2 = L0;
        #pragma unroll 1
        for (int sl = 0; sl < 8; ++sl) {
          if (sl) __syncthreads();
          *(float4*)(bschar + d0) = s0;
          *(float4*)(bschar + d1) = s1;
          *(float4*)(bschar + d2) = s2;
          if (sl < 7) {
            size_t so = (size_t)(sl+1)*8*NN3*8;
            s0 = *(const float4*)(WXP + ((size_t)kb0*NN3 + n0 + nn0p)*8 + so);
            s1 = *(const float4*)(WXP + ((size_t)kb1*NN3 + n0 + nn1p)*8 + so);
            s2 = *(const float4*)(WXP + ((size_t)kb2*NN3 + n0 + nn2p)*8 + so);
          }
          __syncthreads();
          #pragma unroll
          for (int kk = 0; kk < 2; ++kk) {
            int kbl = kk*4 + lk;
            f16x8 b0 = *(const f16x8*)(bschar + ((kbl*1536 + (nw+lr)*16)    ^ (kbl<<4)));
            f16x8 b1 = *(const f16x8*)(bschar + ((kbl*1536 + (nw+16+lr)*16) ^ (kbl<<4)));
            f16x8 b2 = *(const f16x8*)(bschar + ((kbl*1536 + (nw+32+lr)*16) ^ (kbl<<4)));
            f16x8 a = axf[sl*2 + kk];
            L0 = __builtin_amdgcn_mfma_f32_16x16x32_f16(a, b0, L0, 0, 0, 0);
            L1 = __builtin_amdgcn_mfma_f32_16x16x32_f16(a, b1, L1, 0, 0, 0);
            L2 = __builtin_amdgcn_mfma_f32_16x16x32_f16(a, b2, L2, 0, 0, 0);
          }
        }
        alx0 = L0; alx1 = L1; alx2 = L2;
      }
    }
    // --- A-fragments from hb16 (h at step start) via L3: 16 loads in flight, one wait ---
    f16x8 af[16];
    {
      const f16* arow = hb16 + (size_t)(m0 + mw + lr)*DD + lk*8;
      #pragma unroll
      for (int ks = 0; ks < 16; ++ks) ld_b128_sc(&af[ks], arow + ks*32);
      vm_drain();
      __builtin_amdgcn_sched_barrier(0);
    }
    // --- fused j0 GEMM (B resident in LDS) + Y GEMM ---
    f32x4 av0 = {0.f,0.f,0.f,0.f}, av1 = av0, av2 = av0, ty = av0;
    #pragma unroll
    for (int ks = 0; ks < 16; ++ks) {
      int kb = (ks<<2) + lk;
      int x  = (kb & 7) << 4;
      f16x8 b0 = *(const f16x8*)(smem + ((kb*1536 + (nw+lr)*16)    ^ x));
      f16x8 b1 = *(const f16x8*)(smem + ((kb*1536 + (nw+16+lr)*16) ^ x));
      f16x8 b2 = *(const f16x8*)(smem + ((kb*1536 + (nw+32+lr)*16) ^ x));
      f16x8 yb = *(const f16x8*)(LY1P + ((size_t)kb*DD + c0 + lr)*8);
      av0 = __builtin_amdgcn_mfma_f32_16x16x32_f16(af[ks], b0, av0, 0, 0, 0);
      av1 = __builtin_amdgcn_mfma_f32_16x16x32_f16(af[ks], b1, av1, 0, 0, 0);
      av2 = __builtin_amdgcn_mfma_f32_16x16x32_f16(af[ks], b2, av2, 0, 0, 0);
      ty  = __builtin_amdgcn_mfma_f32_16x16x32_f16(af[ks], yb, ty, 0, 0, 0);
    }
    // --- Y finish: tanh, Ly2 multiply, 16-lane reduce, atomics ---
    {
      float part[4][8];
      #pragma unroll
      for (int r2 = 0; r2 < 4; ++r2) {
        float tv = tanh_f(ty[r2]);
        #pragma unroll
        for (int o = 0; o < 8; ++o) part[r2][o] = tv * l2[o];
      }
      #pragma unroll
      for (int ms = 1; ms < 16; ms <<= 1)
        #pragma unroll
        for (int r2 = 0; r2 < 4; ++r2)
          #pragma unroll
          for (int o = 0; o < 8; ++o)
            part[r2][o] += __shfl_xor(part[r2][o], ms, 64);
      if (lr == 0) {
        float* orow = out + (size_t)t*BB*8;
        #pragma unroll
        for (int r2 = 0; r2 < 4; ++r2) {
          int b = m0 + mw + (lk << 2) + r2;
          #pragma unroll
          for (int o = 0; o < 8; ++o)
            atomicAdd(orow + b*8 + o, part[r2][o]);
        }
      }
    }
    if (last) break;
    // --- j0 epilogue (state in registers); stage -> hsA via L3 stores ---
    #pragma unroll
    for (int r2 = 0; r2 < 4; ++r2) {
      float z   = sigmoid_f(av0[r2] + alx0[r2] + bfz);
      float rg  = sigmoid_f(av1[r2] + alx1[r2] + bfr);
      float lin = tanh_f(alx2[r2] + rg*av2[r2] + bfl);
      float kk  = z * (lin - hstage[r2]);
      acc[r2] = kk;
      float hn = hbase[r2] + 0.5f*dtb[r2]*kk;
      hstage[r2] = hn;
      st_f16_sc(hsA + gibase + (size_t)r2*DD, (f16)hn);
    }
    gbar();
    // --- j1..j3 (stage ping-pong: j1 hsA->hsB, j2 hsB->hsA, j3 hsA->hb16) ---
    #pragma unroll
    for (int j = 1; j < 4; ++j) {
      const f16* rbuf = (j == 2) ? hsB : hsA;
      f16x8 afj[16];
      {
        const f16* arow = rbuf + (size_t)(m0 + mw + lr)*DD + lk*8;
        #pragma unroll
        for (int ks = 0; ks < 16; ++ks) ld_b128_sc(&afj[ks], arow + ks*32);
        vm_drain();
        __builtin_amdgcn_sched_barrier(0);
      }
      f32x4 zz = {0.f,0.f,0.f,0.f};
      f32x4 j0a = zz, j1a = zz, j2a = zz;
      #pragma unroll
      for (int ks = 0; ks < 16; ++ks) {
        int kb = (ks<<2) + lk;
        int x  = (kb & 7) << 4;
        f16x8 b0 = *(const f16x8*)(smem + ((kb*1536 + (nw+lr)*16)    ^ x));
        f16x8 b1 = *(const f16x8*)(smem + ((kb*1536 + (nw+16+lr)*16) ^ x));
        f16x8 b2 = *(const f16x8*)(smem + ((kb*1536 + (nw+32+lr)*16) ^ x));
        j0a = __builtin_amdgcn_mfma_f32_16x16x32_f16(afj[ks], b0, j0a, 0, 0, 0);
        j1a = __builtin_amdgcn_mfma_f32_16x16x32_f16(afj[ks], b1, j1a, 0, 0, 0);
        j2a = __builtin_amdgcn_mfma_f32_16x16x32_f16(afj[ks], b2, j2a, 0, 0, 0);
      }
      #pragma unroll
      for (int r2 = 0; r2 < 4; ++r2) {
        float z   = sigmoid_f(j0a[r2] + alx0[r2] + bfz);
        float rg  = sigmoid_f(j1a[r2] + alx1[r2] + bfr);
        float lin = tanh_f(alx2[r2] + rg*j2a[r2] + bfl);
        float kk  = z * (lin - hstage[r2]);
        float hn;
        if (j == 1)      { acc[r2] += 2.f*kk; hn = hbase[r2] + 0.5f*dtb[r2]*kk; }
        else if (j == 2) { acc[r2] += 2.f*kk; hn = hbase[r2] + dtb[r2]*kk; }
        else             { hn = hbase[r2] + dtb[r2]*(acc[r2] + kk)*(1.f/6.f); hbase[r2] = hn; }
        hstage[r2] = hn;
        f16* dbuf = (j == 1) ? hsB : (j == 2) ? hsA : hb16;
        st_f16_sc(dbuf + gibase + (size_t)r2*DD, (f16)hn);
      }
      gbar();
    }
  }
}

extern "C" void kernel_launch(void* const* d_in, const int* in_sizes, int n_in,
                              void* d_out, int out_size, void* d_ws, size_t ws_size,
                              hipStream_t stream)
{
  const float* seq    = (const float*)d_in[0];
  const float* state0 = (const float*)d_in[1];
  const float* Win    = (const float*)d_in[2];
  const float* bin_   = (const float*)d_in[3];
  const float* Wx     = (const float*)d_in[4];
  const float* Wg     = (const float*)d_in[5];
  const float* bg     = (const float*)d_in[6];
  const float* Wlin   = (const float*)d_in[7];
  const float* blin   = (const float*)d_in[8];
  const float* Ly1    = (const float*)d_in[9];
  const float* Ly2    = (const float*)d_in[10];
  char* ws = (char*)d_ws;

  hipFuncSetAttribute((const void*)scan_kernel,
                      hipFuncAttributeMaxDynamicSharedMemorySize, SMEM_BYTES);

  hipMemsetAsync(d_out, 0, (size_t)out_size * sizeof(float), stream);  // y accumulated via atomics
  hipMemsetAsync(d_ws, 0, 8192, stream);                               // barrier words

  pack_kernel<<<dim3(512), dim3(256), 0, stream>>>(Win, Wx, Wg, bg, Wlin, blin, Ly1, ws);
  scan_kernel<<<dim3(NWG), dim3(256), SMEM_BYTES, stream>>>(seq, state0, bin_, Ly2, (float*)d_out, ws);
}